// Round 14
// baseline (16182.532 us; speedup 1.0000x reference)
//
#include <hip/hip_runtime.h>

#define B_  64
#define T_  2048
#define I_  128
#define H_  256
#define G4  1024   // 4*H
#define TC  128    // timestep chunk

// W chunk tiers (chunk = uint4 per gate-row = 8 h-dims; 32 chunks total)
#define HC  12     // chunks 0..11  register-resident (192 dw/thread @ 256-thr)
#define MC  9      // chunks 12..20 LDS-resident (147456 B)
// chunks 21..31 (11) streamed from L2 each step (176 KB/block/step)

typedef float    f32x4 __attribute__((ext_vector_type(4)));
typedef _Float16 f16x8 __attribute__((ext_vector_type(8)));
typedef _Float16 f16x2 __attribute__((ext_vector_type(2)));

__device__ __forceinline__ float dot2f(unsigned w, unsigned h, float acc) {
#if __has_builtin(__builtin_amdgcn_fdot2)
  return __builtin_amdgcn_fdot2(__builtin_bit_cast(f16x2, w),
                                __builtin_bit_cast(f16x2, h), acc, false);
#else
  f16x2 a = __builtin_bit_cast(f16x2, w), b = __builtin_bit_cast(f16x2, h);
  return acc + (float)a[0] * (float)b[0] + (float)a[1] * (float)b[1];
#endif
}

__device__ __forceinline__ unsigned short h16bits(float f) {
  return __builtin_bit_cast(unsigned short, (_Float16)f);
}
__device__ __forceinline__ float sigm(float x) { return 1.f / (1.f + __expf(-x)); }
__device__ __forceinline__ float tanh_fast(float x) { return 2.f / (1.f + __expf(-2.f * x)) - 1.f; }

// ---------------- prep kernels ----------------

__global__ void prep_w(const float* __restrict__ Whh, uint4* __restrict__ wall) {
  int idx = blockIdx.x * 256 + threadIdx.x;
  if (idx >= 32 * 1024) return;
  int c4 = idx >> 10, r = idx & 1023;
  unsigned q[4];
#pragma unroll
  for (int m = 0; m < 4; m++) {
    int kd = 4 * c4 + m;
    unsigned lo = h16bits(Whh[r * 256 + 2 * kd]);
    unsigned hi = h16bits(Whh[r * 256 + 2 * kd + 1]);
    q[m] = lo | (hi << 16);
  }
  wall[c4 * 1024 + r] = make_uint4(q[0], q[1], q[2], q[3]);
}

__global__ void prep_f16(const float* __restrict__ src, _Float16* __restrict__ dst, int n) {
  int i = blockIdx.x * 256 + threadIdx.x;
  if (i < n) dst[i] = (_Float16)src[i];
}

__global__ void prep_bias(const float* __restrict__ bi, const float* __restrict__ bh,
                          float* __restrict__ bias) {
  int i = blockIdx.x * 256 + threadIdx.x;
  if (i < G4) bias[i] = bi[i] + bh[i];
}

// ---------------- projection GEMM (f16 MFMA), xw stored f16 ----------------
template <int K, bool SRC_F32>
__global__ __launch_bounds__(256) void proj_kernel(const void* __restrict__ Asrc,
                                                   const _Float16* __restrict__ Wf,
                                                   const float* __restrict__ bias,
                                                   _Float16* __restrict__ xw, int t0) {
  const int m  = blockIdx.x;
  const int n0 = blockIdx.y * 64;
  const int tid = threadIdx.x;
  const int lane = tid & 63, wv = tid >> 6;

  __shared__ _Float16 As[64][40];
  __shared__ _Float16 Bs[64][40];

  f32x4 acc[4] = {f32x4{0,0,0,0}, f32x4{0,0,0,0}, f32x4{0,0,0,0}, f32x4{0,0,0,0}};

  const int r  = tid >> 2;
  const int kq = (tid & 3) * 8;
  const int r_g = m * 64 + r;
  const int b  = r_g >> 7;          // TC = 128
  const int tc = r_g & (TC - 1);
  long arow;
  if (SRC_F32) arow = (long)(b * T_ + t0 + tc) * K;
  else         arow = (long)r_g * K;

  for (int k0 = 0; k0 < K; k0 += 32) {
    if (SRC_F32) {
      const float* ap = (const float*)Asrc + arow + k0 + kq;
      float4 a0 = *(const float4*)ap;
      float4 a1 = *(const float4*)(ap + 4);
      _Float16* d = &As[r][kq];
      d[0] = (_Float16)a0.x; d[1] = (_Float16)a0.y; d[2] = (_Float16)a0.z; d[3] = (_Float16)a0.w;
      d[4] = (_Float16)a1.x; d[5] = (_Float16)a1.y; d[6] = (_Float16)a1.z; d[7] = (_Float16)a1.w;
    } else {
      const _Float16* ap = (const _Float16*)Asrc + arow + k0 + kq;
      *(uint4*)&As[r][kq] = *(const uint4*)ap;
    }
    *(uint4*)&Bs[r][kq] = *(const uint4*)(Wf + (long)(n0 + r) * K + k0 + kq);
    __syncthreads();

    f16x8 av = *(const f16x8*)&As[wv * 16 + (lane & 15)][(lane >> 4) * 8];
#pragma unroll
    for (int q = 0; q < 4; q++) {
      f16x8 bv = *(const f16x8*)&Bs[q * 16 + (lane & 15)][(lane >> 4) * 8];
      acc[q] = __builtin_amdgcn_mfma_f32_16x16x32_f16(av, bv, acc[q], 0, 0, 0);
    }
    __syncthreads();
  }

  const int row_in = wv * 16 + ((lane >> 4) << 2);
  const int col_in = lane & 15;
#pragma unroll
  for (int q = 0; q < 4; q++) {
#pragma unroll
    for (int i = 0; i < 4; i++) {
      int rr = m * 64 + row_in + i;
      int cc = n0 + q * 16 + col_in;
      xw[(long)rr * G4 + cc] = (_Float16)(acc[q][i] + bias[cc]);
    }
  }
}

// ---------------- recurrent scan ----------------
// One block (256 threads, 4 waves) per (batch, layer-job). Thread j owns gate
// rows {j, j+256, j+512, j+768} = (i,f,g,o)[j] -> gate combine is fully
// thread-local (no exchange), h broadcast via double-buffered LDS, ONE
// barrier per step. 256-thr is the ONLY shape with a 252-VGPR budget
// (backend targets 65536/block_size regardless of launch_bounds arg2 —
// measured: 256->252, 512->128, 1024->64 across r2..r13).
// Tiers: reg 12 chunks (192 dw pinned, peak ~244 regs incl. 2-chunk stream
// in-flight), LDS 9 chunks (147 KB), stream 11 chunks (176 KB/step from the
// shared L2-resident wall), interleaved <=2 chunks in flight.
// A launch carries TWO jobs (L0 chunk k, L1 chunk k-1) on disjoint blocks.

struct ScanJob {
  const _Float16* xw;      // [B*TC][1024] f16
  const uint4*    wall;    // [32][1024]
  const float*    mask;    // [B][256]
  float* hstate; float* cstate;
  _Float16* ychunk;        // layer0 output chunk (or null)
  float* out;              // layer1: d_out base (or null)
  float* hn; float* cn;    // last chunk only (or null)
  int t0; int valid;
};

#define C12(X) X(0) X(1) X(2) X(3) X(4) X(5) X(6) X(7) X(8) X(9) X(10) X(11)

#define LOADW(c) \
  uint4 wi_##c = wall_p[(c) * 1024 + jx]; \
  uint4 wf_##c = wall_p[(c) * 1024 + jx + 256]; \
  uint4 wg_##c = wall_p[(c) * 1024 + jx + 512]; \
  uint4 wo_##c = wall_p[(c) * 1024 + jx + 768];

#define PINW(c) \
  asm volatile("" : "+v"(wi_##c.x), "+v"(wi_##c.y), "+v"(wi_##c.z), "+v"(wi_##c.w), \
                    "+v"(wf_##c.x), "+v"(wf_##c.y), "+v"(wf_##c.z), "+v"(wf_##c.w), \
                    "+v"(wg_##c.x), "+v"(wg_##c.y), "+v"(wg_##c.z), "+v"(wg_##c.w), \
                    "+v"(wo_##c.x), "+v"(wo_##c.y), "+v"(wo_##c.z), "+v"(wo_##c.w));

// 16 fdot2 per chunk over 8 accumulator chains
#define DOT4(vi, vf, vg, vo, c) { uint4 hv = hs4[c]; \
  aix = dot2f(vi.x, hv.x, aix); afx = dot2f(vf.x, hv.x, afx); \
  agx = dot2f(vg.x, hv.x, agx); aox = dot2f(vo.x, hv.x, aox); \
  aiy = dot2f(vi.y, hv.y, aiy); afy = dot2f(vf.y, hv.y, afy); \
  agy = dot2f(vg.y, hv.y, agy); aoy = dot2f(vo.y, hv.y, aoy); \
  aix = dot2f(vi.z, hv.z, aix); afx = dot2f(vf.z, hv.z, afx); \
  agx = dot2f(vg.z, hv.z, agx); aox = dot2f(vo.z, hv.z, aox); \
  aiy = dot2f(vi.w, hv.w, aiy); afy = dot2f(vf.w, hv.w, afy); \
  agy = dot2f(vg.w, hv.w, agy); aoy = dot2f(vo.w, hv.w, aoy); }

#define DOTR(c) DOT4(wi_##c, wf_##c, wg_##c, wo_##c, c)
#define DOTL(c) { uint4 ti = wmid[((c) - HC) * 1024 + jx]; \
                  uint4 tf = wmid[((c) - HC) * 1024 + jx + 256]; \
                  uint4 tg = wmid[((c) - HC) * 1024 + jx + 512]; \
                  uint4 to = wmid[((c) - HC) * 1024 + jx + 768]; \
                  DOT4(ti, tf, tg, to, c) }
#define LOADS(n, c) \
  uint4 si_##n = wsp[((c) - HC - MC) * 1024 + jx]; \
  uint4 sf_##n = wsp[((c) - HC - MC) * 1024 + jx + 256]; \
  uint4 sg_##n = wsp[((c) - HC - MC) * 1024 + jx + 512]; \
  uint4 so_##n = wsp[((c) - HC - MC) * 1024 + jx + 768];
#define DOTS(n, c) DOT4(si_##n, sf_##n, sg_##n, so_##n, c)

__global__ __launch_bounds__(256, 1) void scan_kernel(ScanJob j0, ScanJob j1) {
  ScanJob j = (blockIdx.x < B_) ? j0 : j1;
  if (!j.valid) return;
  const int b  = blockIdx.x & (B_ - 1);
  const int jx = threadIdx.x;          // h index and gate-row base

  __shared__ uint4 wmid[MC * 1024];                        // 147456 B
  __shared__ __align__(16) unsigned short hsb[2][256];     // h f16, dbl-buf

  const uint4* wall_p = j.wall;

  // stage LDS tier (chunks HC..HC+MC-1, coalesced)
#pragma unroll
  for (int i = 0; i < MC * 4; i++)
    wmid[i * 256 + jx] = wall_p[HC * 1024 + i * 256 + jx];

  // register tier: chunks 0..11 x 4 rows = 192 dwords, pinned
  C12(LOADW)
  C12(PINW)

  float c_reg = j.cstate[b * 256 + jx];
  const float mk = j.mask[b * 256 + jx];
  hsb[0][jx] = h16bits(j.hstate[b * 256 + jx]);
  __syncthreads();

  const _Float16* xwb = j.xw + (long)b * TC * G4;
  float xi = (float)xwb[jx],      xf = (float)xwb[jx + 256];
  float xg = (float)xwb[jx + 512], xo = (float)xwb[jx + 768];
  float h_reg = 0.f, hm_prev = 0.f;

  for (int tc = 0; tc < TC; ++tc) {
    const uint4* hs4 = (const uint4*)hsb[tc & 1];

    // prefetch next step's xw
    float ni = 0.f, nf = 0.f, ng = 0.f, no = 0.f;
    if (tc + 1 < TC) {
      const long nx = (long)(tc + 1) * G4;
      ni = (float)xwb[nx + jx];       nf = (float)xwb[nx + jx + 256];
      ng = (float)xwb[nx + jx + 512]; no = (float)xwb[nx + jx + 768];
    }

    // deferred output store for previous step
    if (tc > 0) {
      if (j.ychunk) j.ychunk[(b * TC + tc - 1) * H_ + jx] = (_Float16)hm_prev;
      else          j.out[(long)(b * T_ + j.t0 + tc - 1) * H_ + jx] = hm_prev;
    }

    float aix = xi, aiy = 0.f, afx = xf, afy = 0.f;
    float agx = xg, agy = 0.f, aox = xo, aoy = 0.f;

    const uint4* wsp = wall_p + (HC + MC) * 1024;
    asm volatile("" : "+v"(wsp));   // opaque: no hoist across iterations

    // rolling stream pipeline, <=2 chunks (32 regs) in flight
    LOADS(0, 21) LOADS(1, 22)
    DOTR(0) DOTR(1) DOTR(2) DOTR(3) DOTR(4) DOTR(5)
    DOTR(6) DOTR(7) DOTR(8) DOTR(9) DOTR(10) DOTR(11)
    DOTS(0, 21)
    LOADS(2, 23)
    DOTS(1, 22)
    LOADS(3, 24)
    DOTL(12) DOTL(13)
    DOTS(2, 23)
    LOADS(4, 25)
    DOTL(14)
    DOTS(3, 24)
    LOADS(5, 26)
    DOTL(15)
    DOTS(4, 25)
    LOADS(6, 27)
    DOTL(16)
    DOTS(5, 26)
    LOADS(7, 28)
    DOTL(17)
    DOTS(6, 27)
    LOADS(8, 29)
    DOTL(18)
    DOTS(7, 28)
    LOADS(9, 30)
    DOTL(19)
    DOTS(8, 29)
    LOADS(10, 31)
    DOTL(20)
    DOTS(9, 30)
    DOTS(10, 31)

    // fully thread-local gate combine
    const float ai = aix + aiy, af = afx + afy;
    const float ag = agx + agy, ao = aox + aoy;
    const float ci = sigm(ai), cf = sigm(af);
    const float cg = tanh_fast(ag), co = sigm(ao);
    c_reg = cf * c_reg + ci * cg;
    h_reg = co * tanh_fast(c_reg);
    hsb[(tc + 1) & 1][jx] = h16bits(h_reg);
    hm_prev = h_reg * mk;
    xi = ni; xf = nf; xg = ng; xo = no;
    __syncthreads();
  }

  if (j.ychunk) j.ychunk[(b * TC + TC - 1) * H_ + jx] = (_Float16)hm_prev;
  else          j.out[(long)(b * T_ + j.t0 + TC - 1) * H_ + jx] = hm_prev;
  j.hstate[b * 256 + jx] = h_reg;
  j.cstate[b * 256 + jx] = c_reg;
  if (j.hn) { j.hn[b * 256 + jx] = h_reg; j.cn[b * 256 + jx] = c_reg; }
}

// ---------------- host launch ----------------
extern "C" void kernel_launch(void* const* d_in, const int* in_sizes, int n_in,
                              void* d_out, int out_size, void* d_ws, size_t ws_size,
                              hipStream_t stream) {
  const float* x     = (const float*)d_in[0];
  const float* Wih0  = (const float*)d_in[1];
  const float* Whh0  = (const float*)d_in[2];
  const float* bih0  = (const float*)d_in[3];
  const float* bhh0  = (const float*)d_in[4];
  const float* mask0 = (const float*)d_in[5];
  const float* Wih1  = (const float*)d_in[6];
  const float* Whh1  = (const float*)d_in[7];
  const float* bih1  = (const float*)d_in[8];
  const float* bhh1  = (const float*)d_in[9];
  const float* mask1 = (const float*)d_in[10];

  float* out = (float*)d_out;
  float* hn  = out + (long)B_ * T_ * H_;   // [2][64][256]
  float* cn  = hn + 2 * B_ * H_;

  char* w = (char*)d_ws;
  uint4*    wall0  = (uint4*)w;      w += 512 << 10;   // [32][1024] uint4
  uint4*    wall1  = (uint4*)w;      w += 512 << 10;
  _Float16* wf0    = (_Float16*)w;   w += 256 << 10;
  _Float16* wf1    = (_Float16*)w;   w += 512 << 10;
  float*    bias0  = (float*)w;      w += 4 << 10;
  float*    bias1  = (float*)w;      w += 4 << 10;
  float*    h0s    = (float*)w;      w += 64 << 10;
  float*    c0s    = (float*)w;      w += 64 << 10;
  float*    h1s    = (float*)w;      w += 64 << 10;
  float*    c1s    = (float*)w;      w += 64 << 10;
  _Float16* xw0    = (_Float16*)w;   w += (long)B_ * TC * G4 * 2;   // 16 MB
  _Float16* xw1    = (_Float16*)w;   w += (long)B_ * TC * G4 * 2;   // 16 MB
  _Float16* ybuf   = (_Float16*)w;   w += (long)B_ * TC * H_ * 2;   // 4 MB

  hipMemsetAsync(h0s, 0, 4 * (64 << 10), stream);

  prep_w<<<128, 256, 0, stream>>>(Whh0, wall0);
  prep_w<<<128, 256, 0, stream>>>(Whh1, wall1);
  prep_f16<<<512, 256, 0, stream>>>(Wih0, wf0, G4 * I_);
  prep_f16<<<1024, 256, 0, stream>>>(Wih1, wf1, G4 * H_);
  prep_bias<<<4, 256, 0, stream>>>(bih0, bhh0, bias0);
  prep_bias<<<4, 256, 0, stream>>>(bih1, bhh1, bias1);

  const int nchunk = T_ / TC;  // 16
  for (int k = 0; k <= nchunk; k++) {
    if (k < nchunk) {
      proj_kernel<I_, true><<<dim3(B_ * TC / 64, G4 / 64), 256, 0, stream>>>(
          x, wf0, bias0, xw0, k * TC);
    }
    ScanJob j0, j1;
    // layer 0, chunk k
    j0.xw = xw0; j0.wall = wall0; j0.mask = mask0;
    j0.hstate = h0s; j0.cstate = c0s;
    j0.ychunk = ybuf; j0.out = nullptr;
    j0.hn = (k == nchunk - 1) ? hn : nullptr;
    j0.cn = (k == nchunk - 1) ? cn : nullptr;
    j0.t0 = k * TC; j0.valid = (k < nchunk);
    // layer 1, chunk k-1
    j1.xw = xw1; j1.wall = wall1; j1.mask = mask1;
    j1.hstate = h1s; j1.cstate = c1s;
    j1.ychunk = nullptr; j1.out = out;
    j1.hn = (k == nchunk) ? hn + B_ * H_ : nullptr;
    j1.cn = (k == nchunk) ? cn + B_ * H_ : nullptr;
    j1.t0 = (k - 1) * TC; j1.valid = (k >= 1);

    scan_kernel<<<2 * B_, 256, 0, stream>>>(j0, j1);

    if (k < nchunk) {
      proj_kernel<H_, false><<<dim3(B_ * TC / 64, G4 / 64), 256, 0, stream>>>(
          ybuf, wf1, bias1, xw1, k * TC);
    }
  }
}

// Round 15
// 5336.171 us; speedup vs baseline: 3.0326x; 3.0326x over previous
//
#include <hip/hip_runtime.h>

#define B_  64
#define T_  2048
#define I_  128
#define H_  256
#define G4  1024   // 4*H
#define TC  128    // timestep chunk

// W chunk tiers (chunk = uint4 per gate-row = 8 h-dims; 32 chunks total)
#define HC  23     // chunks 0..22 register-resident (184 dw/thread)
#define MC  9      // chunks 23..31 LDS-resident (147456 B)  -> ZERO streaming

typedef float    f32x4 __attribute__((ext_vector_type(4)));
typedef _Float16 f16x8 __attribute__((ext_vector_type(8)));
typedef _Float16 f16x2 __attribute__((ext_vector_type(2)));

__device__ __forceinline__ float dot2f(unsigned w, unsigned h, float acc) {
#if __has_builtin(__builtin_amdgcn_fdot2)
  return __builtin_amdgcn_fdot2(__builtin_bit_cast(f16x2, w),
                                __builtin_bit_cast(f16x2, h), acc, false);
#else
  f16x2 a = __builtin_bit_cast(f16x2, w), b = __builtin_bit_cast(f16x2, h);
  return acc + (float)a[0] * (float)b[0] + (float)a[1] * (float)b[1];
#endif
}

__device__ __forceinline__ unsigned short h16bits(float f) {
  return __builtin_bit_cast(unsigned short, (_Float16)f);
}
__device__ __forceinline__ float sigm(float x) { return 1.f / (1.f + __expf(-x)); }
__device__ __forceinline__ float tanh_fast(float x) { return 2.f / (1.f + __expf(-2.f * x)) - 1.f; }

// ---------------- prep kernels ----------------

__global__ void prep_w(const float* __restrict__ Whh, uint4* __restrict__ wall) {
  int idx = blockIdx.x * 256 + threadIdx.x;
  if (idx >= 32 * 1024) return;
  int c4 = idx >> 10, r = idx & 1023;
  unsigned q[4];
#pragma unroll
  for (int m = 0; m < 4; m++) {
    int kd = 4 * c4 + m;
    unsigned lo = h16bits(Whh[r * 256 + 2 * kd]);
    unsigned hi = h16bits(Whh[r * 256 + 2 * kd + 1]);
    q[m] = lo | (hi << 16);
  }
  wall[c4 * 1024 + r] = make_uint4(q[0], q[1], q[2], q[3]);
}

__global__ void prep_f16(const float* __restrict__ src, _Float16* __restrict__ dst, int n) {
  int i = blockIdx.x * 256 + threadIdx.x;
  if (i < n) dst[i] = (_Float16)src[i];
}

__global__ void prep_bias(const float* __restrict__ bi, const float* __restrict__ bh,
                          float* __restrict__ bias) {
  int i = blockIdx.x * 256 + threadIdx.x;
  if (i < G4) bias[i] = bi[i] + bh[i];
}

// ---------------- projection GEMM (f16 MFMA), xw stored f16 ----------------
template <int K, bool SRC_F32>
__global__ __launch_bounds__(256) void proj_kernel(const void* __restrict__ Asrc,
                                                   const _Float16* __restrict__ Wf,
                                                   const float* __restrict__ bias,
                                                   _Float16* __restrict__ xw, int t0) {
  const int m  = blockIdx.x;
  const int n0 = blockIdx.y * 64;
  const int tid = threadIdx.x;
  const int lane = tid & 63, wv = tid >> 6;

  __shared__ _Float16 As[64][40];
  __shared__ _Float16 Bs[64][40];

  f32x4 acc[4] = {f32x4{0,0,0,0}, f32x4{0,0,0,0}, f32x4{0,0,0,0}, f32x4{0,0,0,0}};

  const int r  = tid >> 2;
  const int kq = (tid & 3) * 8;
  const int r_g = m * 64 + r;
  const int b  = r_g >> 7;          // TC = 128
  const int tc = r_g & (TC - 1);
  long arow;
  if (SRC_F32) arow = (long)(b * T_ + t0 + tc) * K;
  else         arow = (long)r_g * K;

  for (int k0 = 0; k0 < K; k0 += 32) {
    if (SRC_F32) {
      const float* ap = (const float*)Asrc + arow + k0 + kq;
      float4 a0 = *(const float4*)ap;
      float4 a1 = *(const float4*)(ap + 4);
      _Float16* d = &As[r][kq];
      d[0] = (_Float16)a0.x; d[1] = (_Float16)a0.y; d[2] = (_Float16)a0.z; d[3] = (_Float16)a0.w;
      d[4] = (_Float16)a1.x; d[5] = (_Float16)a1.y; d[6] = (_Float16)a1.z; d[7] = (_Float16)a1.w;
    } else {
      const _Float16* ap = (const _Float16*)Asrc + arow + k0 + kq;
      *(uint4*)&As[r][kq] = *(const uint4*)ap;
    }
    *(uint4*)&Bs[r][kq] = *(const uint4*)(Wf + (long)(n0 + r) * K + k0 + kq);
    __syncthreads();

    f16x8 av = *(const f16x8*)&As[wv * 16 + (lane & 15)][(lane >> 4) * 8];
#pragma unroll
    for (int q = 0; q < 4; q++) {
      f16x8 bv = *(const f16x8*)&Bs[q * 16 + (lane & 15)][(lane >> 4) * 8];
      acc[q] = __builtin_amdgcn_mfma_f32_16x16x32_f16(av, bv, acc[q], 0, 0, 0);
    }
    __syncthreads();
  }

  const int row_in = wv * 16 + ((lane >> 4) << 2);
  const int col_in = lane & 15;
#pragma unroll
  for (int q = 0; q < 4; q++) {
#pragma unroll
    for (int i = 0; i < 4; i++) {
      int rr = m * 64 + row_in + i;
      int cc = n0 + q * 16 + col_in;
      xw[(long)rr * G4 + cc] = (_Float16)(acc[q][i] + bias[cc]);
    }
  }
}

// ---------------- recurrent scan ----------------
// One block (512 threads, 8 waves) per (batch, layer-job). Thread t:
// p=t&255, s=t>>8; rows r0=p+s*256 (i or f), r1=r0+512 (g or o).
//   s=0 -> computes pig = sigm(i)*tanh(g);  s=1 -> (f,o) + owns c/h state.
// FULL W residency: 23 chunks pinned in registers (184 dw/thread) + 9 chunks
// in LDS (147 KB). Physically fits: RF use 8 waves x 64 lanes x ~220 x 4B =
// 450 KB of the 512 KB/CU file, LDS 147 of 160 KB.
// OCCUPANCY CONTROL (the lesson of r8-r14): __launch_bounds__ makes the
// backend plan 2 blocks/CU -> VGPR budget 65536/block_size (measured:
// 256t->252, 512t->128, 1024t->64) and waves_per_eu attrs alongside it are
// ignored. The documented spelling WITHOUT launch_bounds:
//   amdgpu_flat_work_group_size(512,512) + amdgpu_waves_per_eu(2,2)
// demands exactly 2 waves/SIMD = ONE 512-thr block/CU = 256 regs/lane.
// A launch carries TWO jobs (L0 chunk k, L1 chunk k-1) on disjoint blocks.

struct ScanJob {
  const _Float16* xw;      // [B*TC][1024] f16
  const uint4*    wall;    // [32][1024]
  const float*    mask;    // [B][256]
  float* hstate; float* cstate;
  _Float16* ychunk;        // layer0 output chunk (or null)
  float* out;              // layer1: d_out base (or null)
  float* hn; float* cn;    // last chunk only (or null)
  int t0; int valid;
};

#define C23(X) X(0) X(1) X(2) X(3) X(4) X(5) X(6) X(7) X(8) X(9) X(10) X(11) \
               X(12) X(13) X(14) X(15) X(16) X(17) X(18) X(19) X(20) X(21) X(22)

#define LOADW(i) \
  uint4 wA_##i = wall_p[(i) * 1024 + r0]; \
  uint4 wB_##i = wall_p[(i) * 1024 + r1];

#define PINW(i) \
  asm volatile("" : "+v"(wA_##i.x), "+v"(wA_##i.y), "+v"(wA_##i.z), "+v"(wA_##i.w), \
                    "+v"(wB_##i.x), "+v"(wB_##i.y), "+v"(wB_##i.z), "+v"(wB_##i.w));

// 8 dots per chunk over 4 accumulator chains
#define DOT2(gA, gB, c) { uint4 hv = hs4[c]; \
  a0 = dot2f(gA.x, hv.x, a0); a1 = dot2f(gB.x, hv.x, a1); \
  b0 = dot2f(gA.y, hv.y, b0); b1 = dot2f(gB.y, hv.y, b1); \
  a0 = dot2f(gA.z, hv.z, a0); a1 = dot2f(gB.z, hv.z, a1); \
  b0 = dot2f(gA.w, hv.w, b0); b1 = dot2f(gB.w, hv.w, b1); }

#define DOTR(i)  DOT2(wA_##i, wB_##i, i)

__global__
__attribute__((amdgpu_flat_work_group_size(512, 512), amdgpu_waves_per_eu(2, 2)))
void scan_kernel(ScanJob j0, ScanJob j1) {
  ScanJob j = (blockIdx.x < B_) ? j0 : j1;
  if (!j.valid) return;
  const int b = blockIdx.x & (B_ - 1);
  const int t = threadIdx.x;
  const int p = t & 255, s = t >> 8;
  const int r0 = p + s * 256;
  const int r1 = r0 + 512;

  __shared__ uint4 wmid[MC * 1024];                    // 147456 B
  __shared__ __align__(16) unsigned short hsm[256];    // h packed f16
  __shared__ float pig[256];                           // sigm(i)*tanh(g)

  const uint4* wall_p = j.wall;

  // stage LDS tier (chunks HC..31, coalesced)
#pragma unroll
  for (int i = 0; i < MC * 2; i++)
    wmid[i * 512 + t] = wall_p[HC * 1024 + i * 512 + t];

  // register tier: chunks 0..22, rows r0/r1 -> 184 dwords, pinned
  C23(LOADW)
  C23(PINW)

  float c_reg = 0.f, h_reg = 0.f, mk = 0.f;
  if (s == 1) {
    c_reg = j.cstate[b * 256 + p];
    mk    = j.mask[b * 256 + p];
  } else {
    hsm[p] = h16bits(j.hstate[b * 256 + p]);
  }
  __syncthreads();

  const uint4* hs4 = (const uint4*)hsm;
  const _Float16* xwb = j.xw + (long)b * TC * G4;
  float xA = (float)xwb[r0], xB = (float)xwb[r1];
  float hm_prev = 0.f;

  for (int tc = 0; tc < TC; ++tc) {
    // prefetch next step's xw
    float nA = 0.f, nB = 0.f;
    if (tc + 1 < TC) {
      nA = (float)xwb[(long)(tc + 1) * G4 + r0];
      nB = (float)xwb[(long)(tc + 1) * G4 + r1];
    }

    // deferred output store for previous step (drain hides under the dots)
    if (s == 1 && tc > 0) {
      if (j.ychunk) j.ychunk[(b * TC + tc - 1) * H_ + p] = (_Float16)hm_prev;
      else          j.out[(long)(b * T_ + j.t0 + tc - 1) * H_ + p] = hm_prev;
    }

    float a0 = xA, a1 = xB, b0 = 0.f, b1 = 0.f;

    // register tier (23 chunks)
    C23(DOTR)

    // LDS tier (9 chunks)
#pragma unroll
    for (int m = 0; m < MC; m++) {
      uint4 tA = wmid[m * 1024 + r0];
      uint4 tB = wmid[m * 1024 + r1];
      DOT2(tA, tB, HC + m)
    }

    float aF = a0 + b0;   // s=0: pre_i ; s=1: pre_f
    float bF = a1 + b1;   // s=0: pre_g ; s=1: pre_o

    if (s == 0) pig[p] = sigm(aF) * tanh_fast(bF);
    __syncthreads();
    if (s == 1) {
      c_reg = sigm(aF) * c_reg + pig[p];
      h_reg = sigm(bF) * tanh_fast(c_reg);
      hsm[p] = h16bits(h_reg);
      hm_prev = h_reg * mk;
    }
    xA = nA; xB = nB;
    __syncthreads();
  }

  if (s == 1) {
    if (j.ychunk) j.ychunk[(b * TC + TC - 1) * H_ + p] = (_Float16)hm_prev;
    else          j.out[(long)(b * T_ + j.t0 + TC - 1) * H_ + p] = hm_prev;
    j.hstate[b * 256 + p] = h_reg;
    j.cstate[b * 256 + p] = c_reg;
    if (j.hn) { j.hn[b * 256 + p] = h_reg; j.cn[b * 256 + p] = c_reg; }
  }
}

// ---------------- host launch ----------------
extern "C" void kernel_launch(void* const* d_in, const int* in_sizes, int n_in,
                              void* d_out, int out_size, void* d_ws, size_t ws_size,
                              hipStream_t stream) {
  const float* x     = (const float*)d_in[0];
  const float* Wih0  = (const float*)d_in[1];
  const float* Whh0  = (const float*)d_in[2];
  const float* bih0  = (const float*)d_in[3];
  const float* bhh0  = (const float*)d_in[4];
  const float* mask0 = (const float*)d_in[5];
  const float* Wih1  = (const float*)d_in[6];
  const float* Whh1  = (const float*)d_in[7];
  const float* bih1  = (const float*)d_in[8];
  const float* bhh1  = (const float*)d_in[9];
  const float* mask1 = (const float*)d_in[10];

  float* out = (float*)d_out;
  float* hn  = out + (long)B_ * T_ * H_;   // [2][64][256]
  float* cn  = hn + 2 * B_ * H_;

  char* w = (char*)d_ws;
  uint4*    wall0  = (uint4*)w;      w += 512 << 10;   // [32][1024] uint4
  uint4*    wall1  = (uint4*)w;      w += 512 << 10;
  _Float16* wf0    = (_Float16*)w;   w += 256 << 10;
  _Float16* wf1    = (_Float16*)w;   w += 512 << 10;
  float*    bias0  = (float*)w;      w += 4 << 10;
  float*    bias1  = (float*)w;      w += 4 << 10;
  float*    h0s    = (float*)w;      w += 64 << 10;
  float*    c0s    = (float*)w;      w += 64 << 10;
  float*    h1s    = (float*)w;      w += 64 << 10;
  float*    c1s    = (float*)w;      w += 64 << 10;
  _Float16* xw0    = (_Float16*)w;   w += (long)B_ * TC * G4 * 2;   // 16 MB
  _Float16* xw1    = (_Float16*)w;   w += (long)B_ * TC * G4 * 2;   // 16 MB
  _Float16* ybuf   = (_Float16*)w;   w += (long)B_ * TC * H_ * 2;   // 4 MB

  hipMemsetAsync(h0s, 0, 4 * (64 << 10), stream);

  prep_w<<<128, 256, 0, stream>>>(Whh0, wall0);
  prep_w<<<128, 256, 0, stream>>>(Whh1, wall1);
  prep_f16<<<512, 256, 0, stream>>>(Wih0, wf0, G4 * I_);
  prep_f16<<<1024, 256, 0, stream>>>(Wih1, wf1, G4 * H_);
  prep_bias<<<4, 256, 0, stream>>>(bih0, bhh0, bias0);
  prep_bias<<<4, 256, 0, stream>>>(bih1, bhh1, bias1);

  const int nchunk = T_ / TC;  // 16
  for (int k = 0; k <= nchunk; k++) {
    if (k < nchunk) {
      proj_kernel<I_, true><<<dim3(B_ * TC / 64, G4 / 64), 256, 0, stream>>>(
          x, wf0, bias0, xw0, k * TC);
    }
    ScanJob j0, j1;
    // layer 0, chunk k
    j0.xw = xw0; j0.wall = wall0; j0.mask = mask0;
    j0.hstate = h0s; j0.cstate = c0s;
    j0.ychunk = ybuf; j0.out = nullptr;
    j0.hn = (k == nchunk - 1) ? hn : nullptr;
    j0.cn = (k == nchunk - 1) ? cn : nullptr;
    j0.t0 = k * TC; j0.valid = (k < nchunk);
    // layer 1, chunk k-1
    j1.xw = xw1; j1.wall = wall1; j1.mask = mask1;
    j1.hstate = h1s; j1.cstate = c1s;
    j1.ychunk = nullptr; j1.out = out;
    j1.hn = (k == nchunk) ? hn + B_ * H_ : nullptr;
    j1.cn = (k == nchunk) ? cn + B_ * H_ : nullptr;
    j1.t0 = (k - 1) * TC; j1.valid = (k >= 1);

    scan_kernel<<<2 * B_, 512, 0, stream>>>(j0, j1);

    if (k < nchunk) {
      proj_kernel<H_, false><<<dim3(B_ * TC / 64, G4 / 64), 256, 0, stream>>>(
          ybuf, wf1, bias1, xw1, k * TC);
    }
  }
}